// Round 6
// baseline (1002.571 us; speedup 1.0000x reference)
//
#include <hip/hip_runtime.h>
#include <hip/hip_bf16.h>
#include <math.h>

#define CIN 256
#define COUT 256
#define NB 2
#define GN_GROUPS 16

typedef __attribute__((ext_vector_type(8))) short short8;
typedef __attribute__((ext_vector_type(4))) float floatx4;

__device__ __forceinline__ float b2f(unsigned short u) {
  union { unsigned int i; float f; } v;
  v.i = ((unsigned int)u) << 16;
  return v.f;
}
__device__ __forceinline__ unsigned short f2b(float f) {
  union { float f; unsigned int i; } v;
  v.f = f;
  unsigned int r = (v.i + 0x7FFFu + ((v.i >> 16) & 1u)) >> 16;
  return (unsigned short)r;
}
__device__ __forceinline__ float lo2f(unsigned int u) {
  union { unsigned int i; float f; } v;
  v.i = u << 16;
  return v.f;
}
__device__ __forceinline__ float hi2f(unsigned int u) {
  union { unsigned int i; float f; } v;
  v.i = u & 0xffff0000u;
  return v.f;
}
__device__ __forceinline__ unsigned int pk2(float a, float b) {
  union { __hip_bfloat162 h; unsigned int u; } v;
  v.h = __float22bfloat162_rn(float2{a, b});
  return v.u;
}

// ---------------------------------------------------------------------------
// NCHW fp32 -> NHWC bf16 hi + residual lo, one pass. grid (P/64, 4, B).
// ---------------------------------------------------------------------------
__global__ __launch_bounds__(256) void transpose_kernel(
    const float* __restrict__ x, unsigned short* __restrict__ xT,
    unsigned short* __restrict__ xLo, int P) {
  __shared__ float tile[64][65];
  int pBase = blockIdx.x * 64, cBase = blockIdx.y * 64, b = blockIdx.z;
  int t = threadIdx.x;
  int pl = t & 63, ch = t >> 6;
  const float* xb = x + ((size_t)b * CIN + cBase) * P + pBase;
#pragma unroll
  for (int e = 0; e < 16; e++) {
    int c = ch * 16 + e;
    tile[c][pl] = xb[(size_t)c * P + pl];
  }
  __syncthreads();
  size_t obase = ((size_t)b * P + pBase) * CIN + cBase;
  int cl = t & 63, pr = t >> 6;
#pragma unroll
  for (int e = 0; e < 16; e++) {
    int p = pr * 16 + e;
    float v = tile[cl][p];
    unsigned short h = f2b(v);
    xT[obase + (size_t)p * CIN + cl] = h;
    xLo[obase + (size_t)p * CIN + cl] = f2b(v - b2f(h));
  }
}

// ---------------------------------------------------------------------------
// Repack mdconv weight (256,256,3,3) fp32 -> bf16 [oc][K], K = tap*256 + c
// ---------------------------------------------------------------------------
__global__ void repack_w_kernel(const float* __restrict__ w,
                                unsigned short* __restrict__ wt) {
  int idx = blockIdx.x * 256 + threadIdx.x;  // 589824
  int oc = idx / 2304, kk = idx % 2304;
  int k = kk >> 8, c = kk & 255;
  wt[idx] = f2b(w[(size_t)oc * 2304 + c * 9 + k]);
}

// Offset-conv weight (27,256,3,3) -> bf16 wo[sel][tap][cb][oc32][ch32]
__global__ void repack_wo_kernel(const float* __restrict__ w,
                                 unsigned short* __restrict__ wo) {
  int idx = blockIdx.x * 256 + threadIdx.x;  // 2*73728
  int sel = idx / 73728;
  int r = idx % 73728;
  int k = r / 8192;
  int r2 = r % 8192;
  int cbk = r2 / 1024;
  int oc = (r2 / 32) % 32;
  int ch = r2 % 32;
  int c = cbk * 32 + ch;
  float val = (oc < 27) ? w[(size_t)oc * 2304 + c * 9 + k] : 0.0f;
  float hi = b2f(f2b(val));
  wo[idx] = sel ? f2b(val - hi) : f2b(val);
}

// ---------------------------------------------------------------------------
// Offset conv: halo-staged LDS + MFMA, split-bf16, batched over levels.
// ---------------------------------------------------------------------------
struct CoL {
  const unsigned short* xhi;
  const unsigned short* xlo;
  float* om;
  int H, W, Cs, cshift, Rs, P;
};
struct CoB { CoL L[3]; int off[4]; };

__global__ __launch_bounds__(256) void conv_offset_kernel(
    CoB B, const unsigned short* __restrict__ wo,
    const float* __restrict__ bias) {
  __shared__ unsigned short s_hi[204 * 40];
  __shared__ unsigned short s_lo[204 * 40];
  int bx = blockIdx.x;
  int li = (bx >= B.off[1] ? 1 : 0) + (bx >= B.off[2] ? 1 : 0);
  CoL L = B.L[li];
  int local = bx - B.off[li];
  int tpb = L.P / 64;
  int b = local / tpb, pxt = local % tpb;
  int t = threadIdx.x;
  int pbase = pxt * 64;
  int r0 = pbase / L.W;
  int c0 = pbase % L.W;
  int Ct = L.Cs + 2;
  int Npos = Ct * (L.Rs + 2);
  const unsigned short* xhib = L.xhi + (size_t)b * L.P * CIN;
  const unsigned short* xlob = L.xlo + (size_t)b * L.P * CIN;

  int lane = t & 63, wv = t >> 6, quad = lane >> 4, ln = lane & 15;
  int pl = wv * 16 + ln;
  int pi_ = pl >> L.cshift;
  int pj_ = pl & (L.Cs - 1);

  floatx4 acc0 = {0.f, 0.f, 0.f, 0.f}, acc1 = {0.f, 0.f, 0.f, 0.f};

  for (int cb = 0; cb < 8; cb++) {
    __syncthreads();
    for (int e = t; e < Npos * 4; e += 256) {
      int pos = e >> 2, oct = e & 3;
      int r = pos / Ct, c = pos % Ct;
      int gy = r0 - 1 + r, gx = c0 - 1 + c;
      uint4 vhi = {0, 0, 0, 0}, vlo = {0, 0, 0, 0};
      if (gy >= 0 && gy < L.H && gx >= 0 && gx < L.W) {
        size_t off = ((size_t)(gy * L.W + gx)) * CIN + cb * 32 + oct * 8;
        vhi = *(const uint4*)(xhib + off);
        vlo = *(const uint4*)(xlob + off);
      }
      *(uint4*)&s_hi[pos * 40 + oct * 8] = vhi;
      *(uint4*)&s_lo[pos * 40 + oct * 8] = vlo;
    }
    __syncthreads();
#pragma unroll
    for (int tap = 0; tap < 9; tap++) {
      int dy = tap / 3 - 1, dx = tap % 3 - 1;
      const unsigned short* wb0 = wo + (size_t)((0 * 9 + tap) * 8 + cb) * 1024;
      const unsigned short* wb1 = wo + (size_t)((1 * 9 + tap) * 8 + cb) * 1024;
      short8 whi0 = *(const short8*)(wb0 + ln * 32 + quad * 8);
      short8 whi1 = *(const short8*)(wb0 + (16 + ln) * 32 + quad * 8);
      short8 wlo0 = *(const short8*)(wb1 + ln * 32 + quad * 8);
      short8 wlo1 = *(const short8*)(wb1 + (16 + ln) * 32 + quad * 8);
      int pos = (pi_ + dy + 1) * Ct + (pj_ + dx + 1);
      short8 bhi = *(const short8*)&s_hi[pos * 40 + quad * 8];
      short8 blo = *(const short8*)&s_lo[pos * 40 + quad * 8];
      acc0 = __builtin_amdgcn_mfma_f32_16x16x32_bf16(whi0, bhi, acc0, 0, 0, 0);
      acc1 = __builtin_amdgcn_mfma_f32_16x16x32_bf16(whi1, bhi, acc1, 0, 0, 0);
      acc0 = __builtin_amdgcn_mfma_f32_16x16x32_bf16(wlo0, bhi, acc0, 0, 0, 0);
      acc1 = __builtin_amdgcn_mfma_f32_16x16x32_bf16(wlo1, bhi, acc1, 0, 0, 0);
      acc0 = __builtin_amdgcn_mfma_f32_16x16x32_bf16(whi0, blo, acc0, 0, 0, 0);
      acc1 = __builtin_amdgcn_mfma_f32_16x16x32_bf16(whi1, blo, acc1, 0, 0, 0);
    }
  }

  int px = pbase + pl;
#pragma unroll
  for (int i2 = 0; i2 < 2; i2++) {
#pragma unroll
    for (int r = 0; r < 4; r++) {
      int oc = i2 * 16 + quad * 4 + r;
      if (oc < 27) {
        float val = (i2 == 0 ? acc0[r] : acc1[r]) + bias[oc];
        if (oc >= 18) val = 1.f / (1.f + __expf(-val));
        L.om[((size_t)b * 27 + oc) * L.P + px] = val;
      }
    }
  }
}

// ---------------------------------------------------------------------------
// Modulated deformable conv v5: distance-2 register prefetch of gathers,
// distance-1 prefetch of weight fragments, lgkm-only raw barriers (vmem
// prefetch survives the barrier), optional K-split (partial outputs),
// XCD-banded tile swizzle. Batched over a level's paths.
// ---------------------------------------------------------------------------
struct MdP {
  const unsigned short* xT;
  const unsigned short* wt;
  float* outf;
  const float* om;
  int Hi, Wi, Wo, lWo, stride, omStep, omW, omP;
  int ltile, w8, chunksPer, pstride;
};
struct MdBatch { MdP p[3]; int off[4]; };

__global__ __launch_bounds__(256, 3) void mdconv_kernel(MdBatch B) {
  __shared__ float4 s_cw[9][64];
  __shared__ int s_yy[9][64];
  __shared__ int s_xx[9][64];
  __shared__ unsigned short s_col[2][64][40];

  int bx = blockIdx.x;
  int pidx = (bx >= B.off[1] ? 1 : 0) + (bx >= B.off[2] ? 1 : 0);
  MdP P = B.p[pidx];
  int local = bx - B.off[pidx];
  int ntile = 1 << P.ltile;
  // XCD banding over the whole path range (split-major after banding)
  int flat = (local & 7) * P.w8 + (local >> 3);
  int spl = flat >> (P.ltile + 1);
  int rem = flat & (2 * ntile - 1);
  int b = rem >> P.ltile;
  int pxt = rem & (ntile - 1);
  int k0 = spl * P.chunksPer;
  int k1 = k0 + P.chunksPer;
  int Po = P.Wo << P.lWo;
  const unsigned short* xTb = P.xT + (size_t)b * P.Hi * P.Wi * CIN;

  int t = threadIdx.x;
  // Phase 0: sampling metadata for 9 taps x 64 px
  for (int e = t; e < 576; e += 256) {
    int k = e / 64, px = e % 64;
    int p = pxt * 64 + px;
    int i = p >> P.lWo, j = p & (P.Wo - 1);
    int pc = (i * P.omStep) * P.omW + j * P.omStep;
    const float* omb = P.om + (size_t)b * 27 * P.omP;
    float offy = omb[(size_t)(2 * k) * P.omP + pc];
    float offx = omb[(size_t)(2 * k + 1) * P.omP + pc];
    float m = omb[(size_t)(18 + k) * P.omP + pc];
    float py = (float)(i * P.stride) - 1.0f + (float)(k / 3) + offy;
    float pxf = (float)(j * P.stride) - 1.0f + (float)(k % 3) + offx;
    float y0f = floorf(py), x0f = floorf(pxf);
    float wy = py - y0f, wx = pxf - x0f;
    int y0 = (int)y0f, x0 = (int)x0f;
    int y1 = y0 + 1, x1 = x0 + 1;
    float vy0 = (y0 >= 0 && y0 < P.Hi) ? 1.f : 0.f;
    float vy1 = (y1 >= 0 && y1 < P.Hi) ? 1.f : 0.f;
    float vx0 = (x0 >= 0 && x0 < P.Wi) ? 1.f : 0.f;
    float vx1 = (x1 >= 0 && x1 < P.Wi) ? 1.f : 0.f;
    float4 cw;
    cw.x = (1.f - wy) * (1.f - wx) * m * vy0 * vx0;
    cw.y = (1.f - wy) * wx * m * vy0 * vx1;
    cw.z = wy * (1.f - wx) * m * vy1 * vx0;
    cw.w = wy * wx * m * vy1 * vx1;
    s_cw[k][px] = cw;
    int y0c = min(max(y0, 0), P.Hi - 1), y1c = min(max(y1, 0), P.Hi - 1);
    int x0c = min(max(x0, 0), P.Wi - 1), x1c = min(max(x1, 0), P.Wi - 1);
    s_yy[k][px] = y0c | (y1c << 16);
    s_xx[k][px] = x0c | (x1c << 16);
  }
  __syncthreads();

  floatx4 acc[4][4];
#pragma unroll
  for (int i = 0; i < 4; i++)
#pragma unroll
    for (int j = 0; j < 4; j++) acc[i][j] = (floatx4){0.f, 0.f, 0.f, 0.f};

  int lane = t & 63, wv = t >> 6;
  int quad = lane >> 4, ln = lane & 15;
  int wOc = wv * 64;
  int gpx = t >> 2, goct = t & 3;  // gather item: (px, 8-ch octet)

  uint4 gA[4], gB[4];
  short8 afA[4], afB[4];

  auto gather_issue = [&](int k, uint4* g) {
    if (k < k1) {
      int tap = k >> 3, cbk = k & 7;
      int yy = s_yy[tap][gpx], xx = s_xx[tap][gpx];
      int y0 = yy & 0xffff, y1 = (yy >> 16) & 0xffff;
      int x0 = xx & 0xffff, x1 = (xx >> 16) & 0xffff;
      const unsigned short* base = xTb + cbk * 32 + goct * 8;
      g[0] = *(const uint4*)(base + (size_t)(y0 * P.Wi + x0) * CIN);
      g[1] = *(const uint4*)(base + (size_t)(y0 * P.Wi + x1) * CIN);
      g[2] = *(const uint4*)(base + (size_t)(y1 * P.Wi + x0) * CIN);
      g[3] = *(const uint4*)(base + (size_t)(y1 * P.Wi + x1) * CIN);
    }
  };
  auto af_issue = [&](int k, short8* af) {
    if (k < k1) {
      int kBase = (k >> 3) * 256 + (k & 7) * 32;
#pragma unroll
      for (int i = 0; i < 4; i++)
        af[i] = *(const short8*)(P.wt + (size_t)(wOc + i * 16 + ln) * 2304 +
                                 kBase + quad * 8);
    }
  };
  auto combine_store = [&](int k, uint4* g) {
    if (k < k1) {
      float4 cw = s_cw[k >> 3][gpx];
      float r[8];
#pragma unroll
      for (int j = 0; j < 4; j++) {
        unsigned int a = ((unsigned int*)&g[0])[j];
        unsigned int bb = ((unsigned int*)&g[1])[j];
        unsigned int c = ((unsigned int*)&g[2])[j];
        unsigned int d = ((unsigned int*)&g[3])[j];
        r[2 * j] = cw.x * lo2f(a) + cw.y * lo2f(bb) + cw.z * lo2f(c) +
                   cw.w * lo2f(d);
        r[2 * j + 1] = cw.x * hi2f(a) + cw.y * hi2f(bb) + cw.z * hi2f(c) +
                       cw.w * hi2f(d);
      }
      uint4 packed;
      packed.x = pk2(r[0], r[1]);
      packed.y = pk2(r[2], r[3]);
      packed.z = pk2(r[4], r[5]);
      packed.w = pk2(r[6], r[7]);
      *(uint4*)&s_col[k & 1][gpx][goct * 8] = packed;
    }
  };
  auto mfma_step = [&](int k, short8* af) {
    int buf = k & 1;
    short8 bfr[4];
#pragma unroll
    for (int j = 0; j < 4; j++)
      bfr[j] = *(const short8*)&s_col[buf][j * 16 + ln][quad * 8];
#pragma unroll
    for (int i = 0; i < 4; i++)
#pragma unroll
      for (int j = 0; j < 4; j++)
        acc[i][j] = __builtin_amdgcn_mfma_f32_16x16x32_bf16(af[i], bfr[j],
                                                            acc[i][j], 0, 0, 0);
  };
  // LDS-only barrier: drain lgkm, leave vmem prefetches in flight.
  auto lite_barrier = [&]() {
    __builtin_amdgcn_s_waitcnt(0xc07f);
    __builtin_amdgcn_s_barrier();
  };

  // prologue: chunk k0 staged; k0+1 gathers + k0 weights in flight
  gather_issue(k0, gA);
  combine_store(k0, gA);
  gather_issue(k0 + 1, gB);
  af_issue(k0, afA);
  lite_barrier();

  for (int kc = k0; kc < k1; kc += 2) {
    gather_issue(kc + 2, gA);
    af_issue(kc + 1, afB);
    mfma_step(kc, afA);
    combine_store(kc + 1, gB);
    lite_barrier();
    gather_issue(kc + 3, gB);
    af_issue(kc + 2, afA);
    mfma_step(kc + 1, afB);
    combine_store(kc + 2, gA);
    lite_barrier();
  }

  // epilogue: store C (col=lane&15 -> px, row=(lane>>4)*4+reg -> oc)
  float* outp = P.outf + (size_t)spl * P.pstride;
#pragma unroll
  for (int i = 0; i < 4; i++) {
    int ocB = wOc + i * 16 + quad * 4;
#pragma unroll
    for (int j = 0; j < 4; j++) {
      int px = pxt * 64 + j * 16 + ln;
#pragma unroll
      for (int r = 0; r < 4; r++)
        outp[((size_t)b * COUT + ocB + r) * Po + px] = acc[i][j][r];
    }
  }
}

// ---------------------------------------------------------------------------
// Merge K-split partials (into partial 0) + per-(b,c) sum / sumsq
// (+ resize-weighted sum for the high path). Grid (COUT, NB), 256 thr.
// ---------------------------------------------------------------------------
struct MgArg {
  float* f;
  float* sum;
  float* sumsq;
  float* wsum;  // null unless high path
  int P, S, pstride, Wh, lWh, Hro, wb;
};

__global__ __launch_bounds__(256) void merge_stats_kernel(MgArg A) {
  __shared__ float s_prof[64];
  __shared__ float rs[4], rq[4], rw[4];
  int c = blockIdx.x, b = blockIdx.y, tid = threadIdx.x;
  bool hasW = (A.wsum != nullptr);
  if (hasW) {
    if (tid < A.Wh) s_prof[tid] = 0.f;
    __syncthreads();
    if (tid < A.Hro) {
      float r = (float)(A.Wh - 1) / (float)(A.Hro - 1);
      float sy = (float)tid * r;
      int yl = (int)floorf(sy);
      float fy = sy - (float)yl;
      int yh = min(yl + 1, A.Wh - 1);
      atomicAdd(&s_prof[yl], 1.f - fy);
      atomicAdd(&s_prof[yh], fy);
    }
    __syncthreads();
  }
  size_t base = ((size_t)b * COUT + c) * A.P;
  float s1 = 0.f, s2 = 0.f, sw = 0.f;
  for (int p = tid; p < A.P; p += 256) {
    float v = A.f[base + p];
    for (int s = 1; s < A.S; s++) v += A.f[base + (size_t)s * A.pstride + p];
    if (A.wb) A.f[base + p] = v;
    s1 += v;
    s2 += v * v;
    if (hasW) sw += v * s_prof[p >> A.lWh] * s_prof[p & (A.Wh - 1)];
  }
#pragma unroll
  for (int off = 32; off > 0; off >>= 1) {
    s1 += __shfl_down(s1, off, 64);
    s2 += __shfl_down(s2, off, 64);
    sw += __shfl_down(sw, off, 64);
  }
  int lane = tid & 63, wid = tid >> 6;
  if (lane == 0) { rs[wid] = s1; rq[wid] = s2; rw[wid] = sw; }
  __syncthreads();
  if (tid == 0) {
    A.sum[b * COUT + c] = rs[0] + rs[1] + rs[2] + rs[3];
    A.sumsq[b * COUT + c] = rq[0] + rq[1] + rq[2] + rq[3];
    if (hasW) A.wsum[b * COUT + c] = rw[0] + rw[1] + rw[2] + rw[3];
  }
}

// ---------------------------------------------------------------------------
// All per-level scalar prep (GN affines, attention scalars, DyReLU MLP).
// ---------------------------------------------------------------------------
__global__ __launch_bounds__(256) void prep_all_kernel(
    const float* __restrict__ sumM, const float* __restrict__ sqM,
    const float* __restrict__ sumL, const float* __restrict__ sqL,
    const float* __restrict__ sumH, const float* __restrict__ sqH,
    const float* __restrict__ swsum, const float* __restrict__ g_mid,
    const float* __restrict__ be_mid, const float* __restrict__ g_low,
    const float* __restrict__ be_low, const float* __restrict__ g_high,
    const float* __restrict__ be_high, const float* __restrict__ w_sa,
    const float* __restrict__ b_sa, const float* __restrict__ w1,
    const float* __restrict__ b1, const float* __restrict__ w2,
    const float* __restrict__ b2, float invP, float invPh, int hasLow,
    int hasHigh, float invn, float* __restrict__ Am, float* __restrict__ Bm,
    float* __restrict__ Al, float* __restrict__ Bl, float* __restrict__ Ah,
    float* __restrict__ Bh, float* __restrict__ svec,
    float* __restrict__ coef) {
  __shared__ float s_m[3][NB][GN_GROUPS], s_iv[3][NB][GN_GROUPS];
  __shared__ float s_mean[3][NB][COUT];
  __shared__ float s_s[3][NB];
  __shared__ float s_nm[NB][COUT];
  __shared__ float s_h[NB][64];
  int tid = threadIdx.x;

  if (tid < 96) {
    int path = tid / 32, b = (tid >> 4) & 1, g = tid & 15;
    int active = (path == 0) || (path == 1 && hasLow) || (path == 2 && hasHigh);
    if (active) {
      const float* su = path == 0 ? sumM : (path == 1 ? sumL : sumH);
      const float* sq = path == 0 ? sqM : (path == 1 ? sqL : sqH);
      float invN = ((path == 2) ? invPh : invP) * (1.f / 16.f);
      float s = 0.f, q = 0.f;
      for (int c = g * 16; c < g * 16 + 16; c++) {
        s += su[b * COUT + c];
        q += sq[b * COUT + c];
      }
      float m = s * invN;
      float v = q * invN - m * m;
      s_m[path][b][g] = m;
      s_iv[path][b][g] = rsqrtf(v + 1e-5f);
    }
  }
  __syncthreads();
  for (int idx = tid; idx < 3 * NB * COUT; idx += 256) {
    int path = idx / (NB * COUT);
    int r = idx % (NB * COUT);
    int b = r / COUT, c = r % COUT, g = c >> 4;
    int active = (path == 0) || (path == 1 && hasLow) || (path == 2 && hasHigh);
    if (active) {
      const float* ga = path == 0 ? g_mid : (path == 1 ? g_low : g_high);
      const float* be = path == 0 ? be_mid : (path == 1 ? be_low : be_high);
      float a = ga[c] * s_iv[path][b][g];
      float bb = be[c] - s_m[path][b][g] * a;
      float mean;
      if (path == 2)
        mean = a * (swsum[r] * invP) + bb;
      else {
        const float* su = path == 0 ? sumM : sumL;
        mean = a * (su[r] * invP) + bb;
      }
      float* Ad = path == 0 ? Am : (path == 1 ? Al : Ah);
      float* Bd = path == 0 ? Bm : (path == 1 ? Bl : Bh);
      Ad[r] = a;
      Bd[r] = bb;
      s_mean[path][b][c] = mean;
    }
  }
  __syncthreads();
  if (tid < 6) {
    int path = tid >> 1, b = tid & 1;
    int active = (path == 0) || (path == 1 && hasLow) || (path == 2 && hasHigh);
    float s = 0.f;
    if (active) {
      float t = 0.f;
      for (int c = 0; c < COUT; c++) t += s_mean[path][b][c] * w_sa[c];
      t += b_sa[0];
      t = fmaxf(t, 0.0f);
      s = fminf(fmaxf(t + 3.f, 0.f), 6.f) * (1.f / 6.f);
      svec[path * NB + b] = s;
    }
    s_s[path][b] = s;
  }
  __syncthreads();
  for (int idx = tid; idx < NB * COUT; idx += 256) {
    int b = idx / COUT, c = idx % COUT;
    float v = s_s[0][b] * s_mean[0][b][c];
    if (hasLow) v += s_s[1][b] * s_mean[1][b][c];
    if (hasHigh) v += s_s[2][b] * s_mean[2][b][c];
    s_nm[b][c] = v * invn;
  }
  __syncthreads();
  if (tid < NB * 64) {
    int b = tid / 64, j = tid % 64;
    float t = b1[j];
    for (int c = 0; c < COUT; c++) t += s_nm[b][c] * w1[j * COUT + c];
    s_h[b][j] = fmaxf(t, 0.f);
  }
  __syncthreads();
  for (int idx = tid; idx < NB * 1024; idx += 256) {
    int b = idx / 1024, i = idx % 1024;
    float t = b2[i];
    for (int j = 0; j < 64; j++) t += s_h[b][j] * w2[i * 64 + j];
    coef[idx] = fminf(fmaxf(t + 3.f, 0.f), 6.f) * (1.f / 6.f) - 0.5f;
  }
}

// ---------------------------------------------------------------------------
// Fused epilogue: GN-affine+scale of mid (+low) (+bilinear-resized high),
// then DyReLU. One pass over the output.
// ---------------------------------------------------------------------------
__global__ __launch_bounds__(256) void fused_apply_kernel(
    const float* __restrict__ featM, const float* __restrict__ featL,
    const float* __restrict__ featH, const float* __restrict__ Am,
    const float* __restrict__ Bm, const float* __restrict__ Al,
    const float* __restrict__ Bl, const float* __restrict__ Ah,
    const float* __restrict__ Bh, const float* __restrict__ svec,
    const float* __restrict__ coef, float* __restrict__ out, int P, int Ho,
    int Hh, int hasLow, int hasHigh, float invn) {
  int idx = blockIdx.x * 256 + threadIdx.x;
  int bc = idx / P, p = idx % P;
  int b = bc / COUT, c = bc % COUT;
  float v = (featM[idx] * Am[bc] + Bm[bc]) * svec[b];
  if (hasLow) v += (featL[idx] * Al[bc] + Bl[bc]) * svec[2 + b];
  if (hasHigh) {
    int Y = p / Ho, X = p % Ho;
    float r = (float)(Hh - 1) / (float)(Ho - 1);
    float sy = (float)Y * r, sx = (float)X * r;
    int yl = (int)floorf(sy), xl = (int)floorf(sx);
    int yh = min(yl + 1, Hh - 1), xh = min(xl + 1, Hh - 1);
    float wy = sy - (float)yl, wx = sx - (float)xl;
    const float* fp = featH + (size_t)bc * Hh * Hh;
    float t0 = fp[yl * Hh + xl] * (1.f - wx) + fp[yl * Hh + xh] * wx;
    float t1 = fp[yh * Hh + xl] * (1.f - wx) + fp[yh * Hh + xh] * wx;
    v += ((t0 * (1.f - wy) + t1 * wy) * Ah[bc] + Bh[bc]) * svec[4 + b];
  }
  float x = v * invn;
  float a1 = coef[b * 1024 + c] * 2.f + 1.f;
  float b1v = coef[b * 1024 + 256 + c];
  float a2 = coef[b * 1024 + 512 + c] * 2.f;
  float b2v = coef[b * 1024 + 768 + c];
  out[idx] = fmaxf(x * a1 + b1v, x * a2 + b2v);
}

// ---------------------------------------------------------------------------
extern "C" void kernel_launch(void* const* d_in, const int* in_sizes, int n_in,
                              void* d_out, int out_size, void* d_ws,
                              size_t ws_size, hipStream_t stream) {
  (void)in_sizes; (void)n_in; (void)out_size; (void)ws_size;
  const float* x[3] = {(const float*)d_in[0], (const float*)d_in[1],
                       (const float*)d_in[2]};
  const float* w_off = (const float*)d_in[3];
  const float* b_off = (const float*)d_in[4];
  const float* w_mid = (const float*)d_in[5];
  const float* g_mid = (const float*)d_in[6];
  const float* be_mid = (const float*)d_in[7];
  const float* w_low = (const float*)d_in[8];
  const float* g_low = (const float*)d_in[9];
  const float* be_low = (const float*)d_in[10];
  const float* w_high = (const float*)d_in[11];
  const float* g_high = (const float*)d_in[12];
  const float* be_high = (const float*)d_in[13];
  const float* w_sa = (const float*)d_in[14];
  const float* b_sa = (const float*)d_in[15];
  const float* w_dy1 = (const float*)d_in[16];
  const float* b_dy1 = (const float*)d_in[17];
  const float* w_dy2 = (const float*)d_in[18];
  const float* b_dy2 = (const float*)d_in[19];

  float* out = (float*)d_out;
  char* wsb = (char*)d_ws;
  size_t o = 0;
  unsigned short* xT0 = (unsigned short*)(wsb + o); o += 16777216;
  unsigned short* xT1 = (unsigned short*)(wsb + o); o += 4194304;
  unsigned short* xT2 = (unsigned short*)(wsb + o); o += 1048576;
  unsigned short* wtm = (unsigned short*)(wsb + o); o += 1179648;
  unsigned short* wtl = (unsigned short*)(wsb + o); o += 1179648;
  unsigned short* wth = (unsigned short*)(wsb + o); o += 1179648;
  unsigned short* wo  = (unsigned short*)(wsb + o); o += 294912;
  float* om0 = (float*)(wsb + o); o += 3538944;
  float* om1 = (float*)(wsb + o); o += 884736;
  float* om2 = (float*)(wsb + o); o += 221184;
  float* arena = (float*)(wsb + o); o += 44040192;
  float* stats = (float*)(wsb + o); o += 14336;  // 3584 floats
  float* Am = (float*)(wsb + o); o += 2048;
  float* Bm = (float*)(wsb + o); o += 2048;
  float* Al = (float*)(wsb + o); o += 2048;
  float* Bl = (float*)(wsb + o); o += 2048;
  float* Ah = (float*)(wsb + o); o += 2048;
  float* Bh = (float*)(wsb + o); o += 2048;
  float* svec = (float*)(wsb + o); o += 64;
  float* dycoef = (float*)(wsb + o); o += 8192;

  float* sumM = stats;
  float* sqM = stats + 512;
  float* sumL = stats + 1024;
  float* sqL = stats + 1536;
  float* sumH = stats + 2048;
  float* sqH = stats + 2560;
  float* Swsum = stats + 3072;

  // x_lo scratch aliases the feat arena (consumed by conv_offset before
  // any mdconv writes feats).
  unsigned short* xLo0 = (unsigned short*)arena;
  unsigned short* xLo1 = xLo0 + 8388608;
  unsigned short* xLo2 = xLo1 + 2097152;

  const unsigned short* xT[3] = {xT0, xT1, xT2};
  float* om[3] = {om0, om1, om2};

  transpose_kernel<<<dim3(256, 4, NB), 256, 0, stream>>>(x[0], xT0, xLo0, 16384);
  transpose_kernel<<<dim3(64, 4, NB), 256, 0, stream>>>(x[1], xT1, xLo1, 4096);
  transpose_kernel<<<dim3(16, 4, NB), 256, 0, stream>>>(x[2], xT2, xLo2, 1024);
  repack_w_kernel<<<2304, 256, 0, stream>>>(w_mid, wtm);
  repack_w_kernel<<<2304, 256, 0, stream>>>(w_low, wtl);
  repack_w_kernel<<<2304, 256, 0, stream>>>(w_high, wth);
  repack_wo_kernel<<<576, 256, 0, stream>>>(w_off, wo);

  // Batched offset conv over all 3 levels.
  CoB cob;
  cob.L[0] = {xT0, xLo0, om0, 128, 128, 64, 6, 1, 16384};
  cob.L[1] = {xT1, xLo1, om1, 64, 64, 64, 6, 1, 4096};
  cob.L[2] = {xT2, xLo2, om2, 32, 32, 32, 5, 2, 1024};
  cob.off[0] = 0; cob.off[1] = 512; cob.off[2] = 640; cob.off[3] = 672;
  conv_offset_kernel<<<672, 256, 0, stream>>>(cob, wo, b_off);

  const int Hs[3] = {128, 64, 32};
  const int lHs[3] = {7, 6, 5};
  const int Sv[3] = {1, 2, 6};  // K-split per level (72/S even; arena-sized)
  const size_t outOff[3] = {0, 8388608, 10485760};
  const int nterm[3] = {2, 3, 2};

  for (int l = 0; l < 3; l++) {
    int H = Hs[l];
    int P = H * H;
    int hasLow = (l > 0), hasHigh = (l < 2);
    int Hh = H / 2, Ph = Hh * Hh;
    int S = Sv[l];
    float* outl = out + outOff[l];

    int ntileM = P / 64;
    int ntileH = Ph / 64;
    int ltM = lHs[l] * 2 - 6;
    int ltH = ltM - 2;
    int pstrM = NB * COUT * P;
    int pstrH = NB * COUT * Ph;
    int w8M = (NB * ntileM * S) >> 3;
    int w8H = (NB * ntileH * S) >> 3;
    int cpk = 72 / S;

    float* featM = arena;
    float* featL = arena + (size_t)S * pstrM;  // only valid if hasLow
    float* featH = arena + (size_t)S * pstrM * (hasLow ? 2 : 1);

    MdBatch mb;
    int nMid = NB * ntileM * S;
    mb.p[0] = {xT[l], wtm, featM, om[l], H, H, H, lHs[l], 1, 1, H, P,
               ltM, w8M, cpk, pstrM};
    int total = nMid;
    int idx = 1;
    if (hasLow) {
      int Hp = Hs[l - 1];
      mb.p[idx] = {xT[l - 1], wtl, featL, om[l], Hp, Hp, H, lHs[l], 2, 1, H, P,
                   ltM, w8M, cpk, pstrM};
      idx++;
      total += nMid;
    }
    if (hasHigh) {
      mb.p[idx] = {xT[l + 1], wth, featH, om[l], Hh, Hh, Hh, lHs[l] - 1, 1, 2,
                   H, P, ltH, w8H, cpk, pstrH};
      idx++;
      total += NB * ntileH * S;
    }
    mb.off[0] = 0;
    if (l == 0) {            // mid, high
      mb.off[1] = nMid; mb.off[2] = 0x7fffffff; mb.off[3] = 0x7fffffff;
      mb.p[2] = mb.p[1];
    } else if (l == 1) {     // mid, low, high
      mb.off[1] = nMid; mb.off[2] = 2 * nMid; mb.off[3] = 0x7fffffff;
    } else {                 // mid, low
      mb.off[1] = nMid; mb.off[2] = 0x7fffffff; mb.off[3] = 0x7fffffff;
      mb.p[2] = mb.p[1];
    }
    mdconv_kernel<<<total, 256, 0, stream>>>(mb);

    // merge partials + stats
    MgArg ma = {featM, sumM, sqM, nullptr, P, S, pstrM, 1, 0, 1, S > 1};
    merge_stats_kernel<<<dim3(COUT, NB), 256, 0, stream>>>(ma);
    if (hasLow) {
      MgArg malo = {featL, sumL, sqL, nullptr, P, S, pstrM, 1, 0, 1, S > 1};
      merge_stats_kernel<<<dim3(COUT, NB), 256, 0, stream>>>(malo);
    }
    if (hasHigh) {
      MgArg mah = {featH, sumH, sqH, Swsum, Ph, S, pstrH, Hh, lHs[l] - 1, H,
                   S > 1};
      merge_stats_kernel<<<dim3(COUT, NB), 256, 0, stream>>>(mah);
    }

    prep_all_kernel<<<1, 256, 0, stream>>>(
        sumM, sqM, sumL, sqL, sumH, sqH, Swsum, g_mid, be_mid, g_low, be_low,
        g_high, be_high, w_sa, b_sa, w_dy1, b_dy1, w_dy2, b_dy2, 1.0f / P,
        1.0f / Ph, hasLow, hasHigh, 1.0f / nterm[l], Am, Bm, Al, Bl, Ah, Bh,
        svec, dycoef);

    fused_apply_kernel<<<(NB * COUT * P) / 256, 256, 0, stream>>>(
        featM, featL, featH, Am, Bm, Al, Bl, Ah, Bh, svec, dycoef, outl, P, H,
        Hh, hasLow, hasHigh, 1.0f / nterm[l]);
  }
}